// Round 8
// baseline (1824.477 us; speedup 1.0000x reference)
//
#include <hip/hip_runtime.h>

typedef _Float16 half8 __attribute__((ext_vector_type(8)));
typedef float f32x4 __attribute__((ext_vector_type(4)));

#define NBLK 256
#define NTHR 512
#define VD   512
#define HM   1024
#define MPAD 144
#define BSENT 129

// HW_REG_XCC_ID (id=20, offset=0, size=4) -> imm = 20 | (0<<6) | (3<<11)
#define XCC_ID_IMM 6164

// ---------------- workspace layout (total ~56.5 MB) ----------------
static constexpr size_t SZ_SWIH = (size_t)4096 * 512 * 2;
static constexpr size_t SZ_W1K  = (size_t)4096 * 1024 * 2;
static constexpr size_t OFF_SWIH = 0;
static constexpr size_t OFF_SWHH = OFF_SWIH + SZ_SWIH;
static constexpr size_t OFF_PWIH = OFF_SWHH + SZ_W1K;
static constexpr size_t OFF_PWHH = OFF_PWIH + SZ_W1K;
static constexpr size_t OFF_BWIH = OFF_PWHH + SZ_W1K;
static constexpr size_t OFF_BWHH = OFF_BWIH + SZ_W1K;
static constexpr size_t OFF_SB   = OFF_BWHH + SZ_W1K;
static constexpr size_t OFF_PB   = OFF_SB + (size_t)4096 * 4;
static constexpr size_t OFF_BB   = OFF_PB + (size_t)4096 * 4;
static constexpr size_t OFF_X16  = OFF_BB + (size_t)4096 * 4;
static constexpr size_t SZ_X16   = (size_t)64 * MPAD * VD * 2;
static constexpr size_t OFF_STATE = OFF_X16 + SZ_X16;
static constexpr size_t OFF_H    = OFF_STATE;               // [2][144][1024] f16
static constexpr size_t SZ_H     = (size_t)2 * MPAD * HM * 2;
static constexpr size_t OFF_HP   = OFF_H + SZ_H;            // [17][8][1024] f16
static constexpr size_t SZ_HP    = (size_t)17 * 8 * HM * 2;
static constexpr size_t OFF_HB   = OFF_HP + SZ_HP;          // [9][1024] f16
static constexpr size_t SZ_HB    = (size_t)9 * HM * 2;
static constexpr size_t OFF_BAR  = OFF_HB + SZ_HB;          // barrier counters (16 KB)
static constexpr size_t STATE_BYTES = (OFF_BAR + 16384) - OFF_STATE;

// bar[] (uint32 idx), all lines at L3 (touched only via sc1/agent ops):
//   census cen[g]=bar[g*16] (g<16); census barrier csub[i]=bar[256+i*16],
//   cmaster=bar[512], cgen=bar[520];
//   per-step: master=bar[800], gen=bar[832];
//   arrival slots: bar[1024 + g*64 + rank]  (g<16, rank<64);
//   per-XCD gen relay: bar[2048 + g*32].

// ---------------- helpers ----------------
__device__ __forceinline__ half8 h8z() {
    half8 z = {(_Float16)0,(_Float16)0,(_Float16)0,(_Float16)0,
               (_Float16)0,(_Float16)0,(_Float16)0,(_Float16)0};
    return z;
}

__device__ __forceinline__ half8 ld8(const _Float16* p) {
    return *reinterpret_cast<const half8*>(p);
}

__device__ __forceinline__ void lstm_cell(float ip, float fp, float gp, float op,
                                          float& c, float& h) {
    float ig = 1.0f / (1.0f + expf(-ip));
    float fg = 1.0f / (1.0f + expf(-fp));
    float og = 1.0f / (1.0f + expf(-op));
    float gv = tanhf(gp);
    c = fg * c + ig * gv;
    h = og * tanhf(c);
}

// One-shot census barrier: r5/r6-PROVEN full-threadfence barrier, own counters.
__device__ __forceinline__ void gsync_census(unsigned* bar) {
    __syncthreads();
    if (threadIdx.x == 0) {
        __threadfence();
        unsigned a = __hip_atomic_fetch_add(&bar[256 + (blockIdx.x & 15) * 16], 1u,
                                            __ATOMIC_RELAXED, __HIP_MEMORY_SCOPE_AGENT);
        if (a == 15u) {
            unsigned m = __hip_atomic_fetch_add(&bar[512], 1u,
                                                __ATOMIC_RELAXED, __HIP_MEMORY_SCOPE_AGENT);
            if (m == 15u)
                __hip_atomic_store(&bar[520], 1u,
                                   __ATOMIC_RELAXED, __HIP_MEMORY_SCOPE_AGENT);
        }
        while (__hip_atomic_load(&bar[520], __ATOMIC_RELAXED,
                                 __HIP_MEMORY_SCOPE_AGENT) < 1u)
            __builtin_amdgcn_s_sleep(2);
        __threadfence();
    }
    __syncthreads();
}

// Per-step barrier v4 — only r2-r6-PROVEN primitives (sc1 store/load, agent RMW,
// __threadfence, buffer_inv sc0). Per step:
//  1. every block: entry __syncthreads (drains all waves' plain h-stores into the
//     local L2), then ONE sc1 slot store (monotone round number). Causality: the
//     h-stores COMPLETED in L2 before the slot store is even issued.
//  2. per-XCD leader (census rank 0): scans its cnt slots (sc1 loads); complete
//     => all local blocks' h is in this L2 => ONE __threadfence() (wbl2+inv,
//     completion-waited) publishes the whole XCD to L3; then one master RMW;
//     the 8th leader sets global gen.
//  3. broadcast: leaders poll global gen (8 pollers), then sc1-store a per-XCD
//     relay line which their local blocks poll (31 pollers/line, backoff).
//     All relay lines live at L3 (sc1 only => no L2 copy => no wbl2/inv
//     lost-update window, unlike the r7 L2-resident relay that hung).
//  4. every block: per-CU L1 invalidate (L2 already fresh-invalidated by the
//     leader's threadfence, which completed BEFORE gen was set).
__device__ __forceinline__ void gsync4(unsigned* bar, int round, unsigned g,
                                       unsigned rank, unsigned cnt, unsigned nE,
                                       bool leader) {
    const unsigned tgt = (unsigned)(round + 1);
    __syncthreads();
    if (threadIdx.x == 0) {
        if (!leader) {
            __hip_atomic_store(&bar[1024 + g * 64 + rank], tgt,
                               __ATOMIC_RELAXED, __HIP_MEMORY_SCOPE_AGENT);
            while (__hip_atomic_load(&bar[2048 + g * 32], __ATOMIC_RELAXED,
                                     __HIP_MEMORY_SCOPE_AGENT) < tgt)
                __builtin_amdgcn_s_sleep(4);
        } else {
            for (unsigned i = 1; i < cnt; ) {
                unsigned v = __hip_atomic_load(&bar[1024 + g * 64 + i],
                                               __ATOMIC_RELAXED, __HIP_MEMORY_SCOPE_AGENT);
                if (v >= tgt) ++i;
                else __builtin_amdgcn_s_sleep(1);
            }
            __threadfence();               // wbl2+inv: whole XCD's h -> L3, completed
            unsigned m = __hip_atomic_fetch_add(&bar[800], 1u,
                                                __ATOMIC_RELAXED, __HIP_MEMORY_SCOPE_AGENT);
            if (m == tgt * nE - 1u)
                __hip_atomic_store(&bar[832], tgt,
                                   __ATOMIC_RELAXED, __HIP_MEMORY_SCOPE_AGENT);
            while (__hip_atomic_load(&bar[832], __ATOMIC_RELAXED,
                                     __HIP_MEMORY_SCOPE_AGENT) < tgt)
                __builtin_amdgcn_s_sleep(2);
            __hip_atomic_store(&bar[2048 + g * 32], tgt,
                               __ATOMIC_RELAXED, __HIP_MEMORY_SCOPE_AGENT);
        }
        // per-CU L1 invalidate so post-barrier plain loads refetch via (fresh) L2
        asm volatile("buffer_inv sc0\n\ts_waitcnt vmcnt(0)" ::: "memory");
    }
    __syncthreads();
}

// ---------------- prep kernels ----------------
__global__ void k_cvt(const float* __restrict__ s, _Float16* __restrict__ d, int n) {
    for (int i = blockIdx.x * blockDim.x + threadIdx.x; i < n; i += gridDim.x * blockDim.x)
        d[i] = (_Float16)s[i];
}

__global__ void k_bias(const float* a1, const float* a2, const float* b1, const float* b2,
                       const float* c1, const float* c2,
                       float* sb, float* pb, float* bb) {
    int i = blockIdx.x * blockDim.x + threadIdx.x;
    if (i < 4096) {
        sb[i] = a1[i] + a2[i];
        pb[i] = b1[i] + b2[i];
        bb[i] = c1[i] + c2[i];
    }
}

// X16[t][row][d]; row 0 = headline, rows 1..128 = body sentences, 129..143 zero pad
__global__ void k_gather(const int* __restrict__ head, const int* __restrict__ body,
                         const float* __restrict__ emb, _Float16* __restrict__ X16) {
    const int total = 64 * MPAD * VD;
    for (int idx = blockIdx.x * blockDim.x + threadIdx.x; idx < total;
         idx += gridDim.x * blockDim.x) {
        int d   = idx & (VD - 1);
        int rt  = idx >> 9;
        int row = rt % MPAD;
        int t   = rt / MPAD;
        float v = 0.0f;
        if (row == 0)         v = emb[(size_t)head[t] * VD + d];
        else if (row < BSENT) v = emb[(size_t)body[(row - 1) * 64 + t] * VD + d];
        X16[idx] = (_Float16)v;
    }
}

// ---------------- main persistent kernel ----------------
// 256 blocks x 512 thr (8 waves). Block owns 4 hidden units (16 gate cols).
// Weights live in LDS (64 KB wfrag) — immune to the per-step L2 invalidate.
// Sentence: 9 row-tiles of 16; waves g=wv&3 own tiles {g, g+4, (g==0: 8)};
// K(1536) split 2-way across kh=wv>>2; epilogue reduces the two K-half partials.
extern "C" __global__ void __launch_bounds__(NTHR, 2)
k_main(const _Float16* __restrict__ sWih, const _Float16* __restrict__ sWhh,
       const _Float16* __restrict__ pWih, const _Float16* __restrict__ pWhh,
       const _Float16* __restrict__ bWih, const _Float16* __restrict__ bWhh,
       const float* __restrict__ sb, const float* __restrict__ pb, const float* __restrict__ bb,
       const _Float16* __restrict__ X16,
       _Float16* H, _Float16* HP, _Float16* HB,
       float* out, unsigned* bar)
{
    __shared__ float lds[8][3][16][17];
    __shared__ half8 wfrag[4096];     // 64 KB: B-fragments for the current stage

    const int tid  = threadIdx.x;
    const int lane = tid & 63;
    const int wv   = tid >> 6;        // 0..7
    const int g    = wv & 3;
    const int kh   = wv >> 2;         // K-half
    const int l15  = lane & 15;
    const int krow = lane >> 4;       // 0..3
    const int rr   = lane >> 2;       // epilogue row 0..15
    const int mm   = lane & 3;        // epilogue col 0..3
    const int ubase = blockIdx.x * 4;
    const int uo    = ubase + mm;
    const int grow  = (l15 >> 2) * HM + ubase + (l15 & 3);  // weight row for B col l15

    const float sbi = sb[uo], sbf = sb[1024 + uo], sbg = sb[2048 + uo], sbo = sb[3072 + uo];
    const float pbi = pb[uo], pbf = pb[1024 + uo], pbg = pb[2048 + uo], pbo = pb[3072 + uo];
    const float bbi = bb[uo], bbf = bb[1024 + uo], bbg = bb[2048 + uo], bbo = bb[3072 + uo];

    const int rA0 = g * 16 + l15;     // tile g
    const int rA1 = rA0 + 64;         // tile g+4
    const int rA2 = 128 + l15;        // tile 8 (g==0 waves)

    float c_main = 0.f, c_t8 = 0.f, c_para = 0.f, c_body = 0.f, rhid_reg = 0.f;
    int round = 0;

    // ---- census: learn XCD, blocks-per-XCD, per-XCD rank (leader = rank 0) ----
    unsigned myG = 0, myRank = 0, myCnt = 0, myNE = 0;
    bool leader = false;
    {
        unsigned xcc = __builtin_amdgcn_s_getreg(XCC_ID_IMM) & 15u;
        unsigned rk = 0;
        if (tid == 0) {
            rk = __hip_atomic_fetch_add(&bar[xcc * 16], 1u,
                                        __ATOMIC_RELAXED, __HIP_MEMORY_SCOPE_AGENT);
        }
        // ---- stage sentence-stage weight fragments into LDS while census settles ----
#pragma unroll
        for (int q = 0; q < 2; ++q) {
            int kt = wv + q * 8;
            wfrag[kt * 64 + lane] = ld8(sWih + (size_t)grow * VD + kt * 32 + krow * 8);
        }
#pragma unroll
        for (int q = 0; q < 4; ++q) {
            int kt = wv + q * 8;
            wfrag[(16 + kt) * 64 + lane] = ld8(sWhh + (size_t)grow * HM + kt * 32 + krow * 8);
        }
        gsync_census(bar);
        if (tid == 0) {
            myG = xcc;
            myRank = rk;
            leader = (rk == 0u);
            myCnt = __hip_atomic_load(&bar[xcc * 16], __ATOMIC_RELAXED,
                                      __HIP_MEMORY_SCOPE_AGENT);
            myNE = 0;
            for (int i = 0; i < 16; ++i) {
                unsigned c = __hip_atomic_load(&bar[i * 16], __ATOMIC_RELAXED,
                                               __HIP_MEMORY_SCOPE_AGENT);
                myNE += (c != 0u) ? 1u : 0u;
            }
        }
    }

    // ================= sentence LSTM: 64 steps, batch 129 (pad 144) =================
#pragma unroll 1
    for (int t = 0; t < 64; ++t) {
        const _Float16* Xt = X16 + (size_t)t * MPAD * VD;
        const _Float16* Hr = H + (size_t)(t & 1) * MPAD * HM;
        _Float16*       Hw = H + (size_t)((t + 1) & 1) * MPAD * HM;

        f32x4 a0 = {0.f,0.f,0.f,0.f}, a1 = {0.f,0.f,0.f,0.f}, a2 = {0.f,0.f,0.f,0.f};
        if (kh == 0) {
            // x part: K 0..511 (slots 0..15)
#pragma unroll
            for (int kt = 0; kt < 16; ++kt) {
                const int kk = kt * 32 + krow * 8;
                half8 b  = wfrag[kt * 64 + lane];
                half8 x0 = ld8(Xt + (size_t)rA0 * VD + kk);
                half8 x1 = ld8(Xt + (size_t)rA1 * VD + kk);
                a0 = __builtin_amdgcn_mfma_f32_16x16x32_f16(x0, b, a0, 0, 0, 0);
                a1 = __builtin_amdgcn_mfma_f32_16x16x32_f16(x1, b, a1, 0, 0, 0);
                if (g == 0) {
                    half8 x2 = ld8(Xt + (size_t)rA2 * VD + kk);
                    a2 = __builtin_amdgcn_mfma_f32_16x16x32_f16(x2, b, a2, 0, 0, 0);
                }
            }
            // h part: K-tiles 0..7 (slots 16..23)
#pragma unroll
            for (int kt = 0; kt < 8; ++kt) {
                const int kk = kt * 32 + krow * 8;
                half8 b  = wfrag[(16 + kt) * 64 + lane];
                half8 h0 = ld8(Hr + (size_t)rA0 * HM + kk);
                half8 h1 = ld8(Hr + (size_t)rA1 * HM + kk);
                a0 = __builtin_amdgcn_mfma_f32_16x16x32_f16(h0, b, a0, 0, 0, 0);
                a1 = __builtin_amdgcn_mfma_f32_16x16x32_f16(h1, b, a1, 0, 0, 0);
                if (g == 0) {
                    half8 h2 = ld8(Hr + (size_t)rA2 * HM + kk);
                    a2 = __builtin_amdgcn_mfma_f32_16x16x32_f16(h2, b, a2, 0, 0, 0);
                }
            }
        } else {
            // h part: K-tiles 8..31 (slots 24..47)
#pragma unroll
            for (int kt = 0; kt < 24; ++kt) {
                const int kk = (8 + kt) * 32 + krow * 8;
                half8 b  = wfrag[(24 + kt) * 64 + lane];
                half8 h0 = ld8(Hr + (size_t)rA0 * HM + kk);
                half8 h1 = ld8(Hr + (size_t)rA1 * HM + kk);
                a0 = __builtin_amdgcn_mfma_f32_16x16x32_f16(h0, b, a0, 0, 0, 0);
                a1 = __builtin_amdgcn_mfma_f32_16x16x32_f16(h1, b, a1, 0, 0, 0);
                if (g == 0) {
                    half8 h2 = ld8(Hr + (size_t)rA2 * HM + kk);
                    a2 = __builtin_amdgcn_mfma_f32_16x16x32_f16(h2, b, a2, 0, 0, 0);
                }
            }
        }
        // stash K-half partials
#pragma unroll
        for (int q = 0; q < 4; ++q) {
            lds[wv][0][krow * 4 + q][l15] = a0[q];
            lds[wv][1][krow * 4 + q][l15] = a1[q];
        }
        if (g == 0) {
#pragma unroll
            for (int q = 0; q < 4; ++q) lds[wv][2][krow * 4 + q][l15] = a2[q];
        }
        __syncthreads();
        // epilogue: wave T reduces the two K-half partials of tile T
        {
            const int T  = wv;
            const int wA = (T < 4) ? T     : T - 4;
            const int wB = (T < 4) ? T + 4 : T;
            const int jj = (T < 4) ? 0 : 1;
            const int rowg = T * 16 + rr;
            if (rowg < BSENT) {
                float ip = lds[wA][jj][rr][ 0 + mm] + lds[wB][jj][rr][ 0 + mm] + sbi;
                float fp = lds[wA][jj][rr][ 4 + mm] + lds[wB][jj][rr][ 4 + mm] + sbf;
                float gp = lds[wA][jj][rr][ 8 + mm] + lds[wB][jj][rr][ 8 + mm] + sbg;
                float op = lds[wA][jj][rr][12 + mm] + lds[wB][jj][rr][12 + mm] + sbo;
                float h;
                lstm_cell(ip, fp, gp, op, c_main, h);
                if (t == 63 && wv == 0 && rr == 0) rhid_reg = h;
                Hw[(size_t)rowg * HM + uo] = (_Float16)h;
            }
        }
        if (wv == 0) {   // tile 8: only row 128 valid
            const int rowg = 128 + rr;
            if (rowg < BSENT) {
                float ip = lds[0][2][rr][ 0 + mm] + lds[4][2][rr][ 0 + mm] + sbi;
                float fp = lds[0][2][rr][ 4 + mm] + lds[4][2][rr][ 4 + mm] + sbf;
                float gp = lds[0][2][rr][ 8 + mm] + lds[4][2][rr][ 8 + mm] + sbg;
                float op = lds[0][2][rr][12 + mm] + lds[4][2][rr][12 + mm] + sbo;
                float h;
                lstm_cell(ip, fp, gp, op, c_t8, h);
                Hw[(size_t)rowg * HM + uo] = (_Float16)h;
            }
        }
        gsync4(bar, round, myG, myRank, myCnt, myNE, leader); ++round;
    }

    // ---- stage paragraph-stage weights: ih kt0..31 -> slot kt, hh -> slot 32+kt ----
#pragma unroll
    for (int q = 0; q < 4; ++q) {
        int kt = wv + q * 8;
        wfrag[kt * 64 + lane]        = ld8(pWih + (size_t)grow * HM + kt * 32 + krow * 8);
        wfrag[(32 + kt) * 64 + lane] = ld8(pWhh + (size_t)grow * HM + kt * 32 + krow * 8);
    }
    __syncthreads();

    // ================= paragraph LSTM: 16 steps, batch 8 (pad 16) =================
    const _Float16* Hs = H;   // sentence-final h landed in buffer 0
#pragma unroll 1
    for (int s = 0; s < 16; ++s) {
        const _Float16* HPr = HP + (size_t)s * 8 * HM;
        _Float16*       HPw = HP + (size_t)(s + 1) * 8 * HM;
        f32x4 acc = {0.f,0.f,0.f,0.f};
        if (wv < 4) {
            const int rs = 1 + l15 * 16 + s;                  // sent_h[p=l15][s]
#pragma unroll
            for (int k = 0; k < 8; ++k) {
                const int kt = wv * 8 + k;
                const int kk = kt * 32 + krow * 8;
                half8 b = wfrag[kt * 64 + lane];
                half8 a = h8z();
                if (l15 < 8) a = ld8(Hs + (size_t)rs * HM + kk);
                acc = __builtin_amdgcn_mfma_f32_16x16x32_f16(a, b, acc, 0, 0, 0);
            }
        } else {
#pragma unroll
            for (int k = 0; k < 8; ++k) {
                const int kt = (wv - 4) * 8 + k;
                const int kk = kt * 32 + krow * 8;
                half8 b = wfrag[(32 + kt) * 64 + lane];
                half8 a = h8z();
                if (l15 < 8) a = ld8(HPr + (size_t)l15 * HM + kk);
                acc = __builtin_amdgcn_mfma_f32_16x16x32_f16(a, b, acc, 0, 0, 0);
            }
        }
#pragma unroll
        for (int q = 0; q < 4; ++q) lds[wv][0][krow * 4 + q][l15] = acc[q];
        __syncthreads();
        if (wv == 0 && rr < 8) {
            float ip = pbi, fp = pbf, gp = pbg, op = pbo;
#pragma unroll
            for (int w = 0; w < 8; ++w) {
                ip += lds[w][0][rr][ 0 + mm];
                fp += lds[w][0][rr][ 4 + mm];
                gp += lds[w][0][rr][ 8 + mm];
                op += lds[w][0][rr][12 + mm];
            }
            float h;
            lstm_cell(ip, fp, gp, op, c_para, h);
            HPw[(size_t)rr * HM + uo] = (_Float16)h;
        }
        gsync4(bar, round, myG, myRank, myCnt, myNE, leader); ++round;
    }

    // ---- stage body-stage weights (same slot scheme) ----
#pragma unroll
    for (int q = 0; q < 4; ++q) {
        int kt = wv + q * 8;
        wfrag[kt * 64 + lane]        = ld8(bWih + (size_t)grow * HM + kt * 32 + krow * 8);
        wfrag[(32 + kt) * 64 + lane] = ld8(bWhh + (size_t)grow * HM + kt * 32 + krow * 8);
    }
    __syncthreads();

    // ================= body LSTM: 8 steps, batch 1 =================
    const _Float16* HPf = HP + (size_t)16 * 8 * HM;   // para-final h
#pragma unroll 1
    for (int t = 0; t < 8; ++t) {
        const _Float16* HBr = HB + (size_t)t * HM;
        _Float16*       HBw = HB + (size_t)(t + 1) * HM;
        f32x4 acc = {0.f,0.f,0.f,0.f};
        if (wv < 4) {
#pragma unroll
            for (int k = 0; k < 8; ++k) {
                const int kt = wv * 8 + k;
                const int kk = kt * 32 + krow * 8;
                half8 b = wfrag[kt * 64 + lane];
                half8 a = h8z();
                if (l15 == 0) a = ld8(HPf + (size_t)t * HM + kk);
                acc = __builtin_amdgcn_mfma_f32_16x16x32_f16(a, b, acc, 0, 0, 0);
            }
        } else {
#pragma unroll
            for (int k = 0; k < 8; ++k) {
                const int kt = (wv - 4) * 8 + k;
                const int kk = kt * 32 + krow * 8;
                half8 b = wfrag[(32 + kt) * 64 + lane];
                half8 a = h8z();
                if (l15 == 0) a = ld8(HBr + kk);
                acc = __builtin_amdgcn_mfma_f32_16x16x32_f16(a, b, acc, 0, 0, 0);
            }
        }
#pragma unroll
        for (int q = 0; q < 4; ++q) lds[wv][0][krow * 4 + q][l15] = acc[q];
        __syncthreads();
        if (wv == 0 && rr == 0) {   // lanes 0..3
            float ip = bbi, fp = bbf, gp = bbg, op = bbo;
#pragma unroll
            for (int w = 0; w < 8; ++w) {
                ip += lds[w][0][0][ 0 + mm];
                fp += lds[w][0][0][ 4 + mm];
                gp += lds[w][0][0][ 8 + mm];
                op += lds[w][0][0][12 + mm];
            }
            float h;
            lstm_cell(ip, fp, gp, op, c_body, h);
            HBw[uo] = (_Float16)h;
            if (t == 7) {
                out[uo]        = h;          // h_body
                out[1024 + uo] = rhid_reg;   // r_hidden
            }
        }
        gsync4(bar, round, myG, myRank, myCnt, myNE, leader); ++round;
    }
}

// ---------------- host ----------------
extern "C" void kernel_launch(void* const* d_in, const int* in_sizes, int n_in,
                              void* d_out, int out_size, void* d_ws, size_t ws_size,
                              hipStream_t stream) {
    const int*   head  = (const int*)d_in[0];
    const int*   body  = (const int*)d_in[1];
    const float* emb   = (const float*)d_in[2];
    const float* sWihF = (const float*)d_in[3];
    const float* sWhhF = (const float*)d_in[4];
    const float* sbih  = (const float*)d_in[5];
    const float* sbhh  = (const float*)d_in[6];
    const float* pWihF = (const float*)d_in[7];
    const float* pWhhF = (const float*)d_in[8];
    const float* pbih  = (const float*)d_in[9];
    const float* pbhh  = (const float*)d_in[10];
    const float* bWihF = (const float*)d_in[11];
    const float* bWhhF = (const float*)d_in[12];
    const float* bbih  = (const float*)d_in[13];
    const float* bbhh  = (const float*)d_in[14];

    char* ws = (char*)d_ws;
    _Float16* sWih16 = (_Float16*)(ws + OFF_SWIH);
    _Float16* sWhh16 = (_Float16*)(ws + OFF_SWHH);
    _Float16* pWih16 = (_Float16*)(ws + OFF_PWIH);
    _Float16* pWhh16 = (_Float16*)(ws + OFF_PWHH);
    _Float16* bWih16 = (_Float16*)(ws + OFF_BWIH);
    _Float16* bWhh16 = (_Float16*)(ws + OFF_BWHH);
    float*    sbp    = (float*)(ws + OFF_SB);
    float*    pbp    = (float*)(ws + OFF_PB);
    float*    bbp    = (float*)(ws + OFF_BB);
    _Float16* X16    = (_Float16*)(ws + OFF_X16);
    _Float16* Hp     = (_Float16*)(ws + OFF_H);
    _Float16* HPp    = (_Float16*)(ws + OFF_HP);
    _Float16* HBp    = (_Float16*)(ws + OFF_HB);
    unsigned* barp   = (unsigned*)(ws + OFF_BAR);
    float*    outp   = (float*)d_out;

    hipMemsetAsync(ws + OFF_STATE, 0, STATE_BYTES, stream);
    k_cvt<<<512, 256, 0, stream>>>(sWihF, sWih16, 4096 * 512);
    k_cvt<<<1024, 256, 0, stream>>>(sWhhF, sWhh16, 4096 * 1024);
    k_cvt<<<1024, 256, 0, stream>>>(pWihF, pWih16, 4096 * 1024);
    k_cvt<<<1024, 256, 0, stream>>>(pWhhF, pWhh16, 4096 * 1024);
    k_cvt<<<1024, 256, 0, stream>>>(bWihF, bWih16, 4096 * 1024);
    k_cvt<<<1024, 256, 0, stream>>>(bWhhF, bWhh16, 4096 * 1024);
    k_bias<<<16, 256, 0, stream>>>(sbih, sbhh, pbih, pbhh, bbih, bbhh, sbp, pbp, bbp);
    k_gather<<<2048, 256, 0, stream>>>(head, body, emb, X16);

    void* args[] = { &sWih16, &sWhh16, &pWih16, &pWhh16, &bWih16, &bWhh16,
                     &sbp, &pbp, &bbp, &X16,
                     &Hp, &HPp, &HBp, &outp, &barp };
    hipError_t err = hipLaunchCooperativeKernel(reinterpret_cast<void*>(k_main),
                                                dim3(NBLK), dim3(NTHR), args, 0, stream);
    if (err != hipSuccess) {
        // 256 blocks x 512 thr = 8 waves/CU on 256 CUs are co-resident; best-effort fallback.
        k_main<<<NBLK, NTHR, 0, stream>>>(sWih16, sWhh16, pWih16, pWhh16, bWih16, bWhh16,
                                          sbp, pbp, bbp, X16,
                                          Hp, HPp, HBp, outp, barp);
    }
}

// Round 9
// 1365.011 us; speedup vs baseline: 1.3366x; 1.3366x over previous
//
#include <hip/hip_runtime.h>

typedef _Float16 half8 __attribute__((ext_vector_type(8)));
typedef float f32x4 __attribute__((ext_vector_type(4)));

#define NBLK 256
#define NTHR 512
#define VD   512
#define HM   1024
#define MPAD 144
#define BSENT 129

// HW_REG_XCC_ID (id=20, offset=0, size=4) -> imm = 20 | (0<<6) | (3<<11)
#define XCC_ID_IMM 6164

// ---------------- workspace layout (total ~56.5 MB) ----------------
static constexpr size_t SZ_SWIH = (size_t)4096 * 512 * 2;
static constexpr size_t SZ_W1K  = (size_t)4096 * 1024 * 2;
static constexpr size_t OFF_SWIH = 0;
static constexpr size_t OFF_SWHH = OFF_SWIH + SZ_SWIH;
static constexpr size_t OFF_PWIH = OFF_SWHH + SZ_W1K;
static constexpr size_t OFF_PWHH = OFF_PWIH + SZ_W1K;
static constexpr size_t OFF_BWIH = OFF_PWHH + SZ_W1K;
static constexpr size_t OFF_BWHH = OFF_BWIH + SZ_W1K;
static constexpr size_t OFF_SB   = OFF_BWHH + SZ_W1K;
static constexpr size_t OFF_PB   = OFF_SB + (size_t)4096 * 4;
static constexpr size_t OFF_BB   = OFF_PB + (size_t)4096 * 4;
static constexpr size_t OFF_X16  = OFF_BB + (size_t)4096 * 4;
static constexpr size_t SZ_X16   = (size_t)64 * MPAD * VD * 2;
static constexpr size_t OFF_STATE = OFF_X16 + SZ_X16;
static constexpr size_t OFF_H    = OFF_STATE;               // [2][144][1024] f16
static constexpr size_t SZ_H     = (size_t)2 * MPAD * HM * 2;
static constexpr size_t OFF_HP   = OFF_H + SZ_H;            // [17][8][1024] f16
static constexpr size_t SZ_HP    = (size_t)17 * 8 * HM * 2;
static constexpr size_t OFF_HB   = OFF_HP + SZ_HP;          // [9][1024] f16
static constexpr size_t SZ_HB    = (size_t)9 * HM * 2;
static constexpr size_t OFF_BAR  = OFF_HB + SZ_HB;          // barrier counters (16 KB)
static constexpr size_t STATE_BYTES = (OFF_BAR + 16384) - OFF_STATE;

// bar[] (uint32 idx), all accessed sc1/agent (L3-resident):
//   census cen[g]=bar[g*16] (g<16); census barrier csub[i]=bar[256+i*16],
//   cmaster=bar[512], cgen=bar[520];
//   per-step local arrival slots: bar[1024 + g*64 + rank] (g<16, rank<64);
//   per-step global done-flags:   bar[3072 + g*16]        (64B apart).

// ---------------- helpers ----------------
__device__ __forceinline__ half8 h8z() {
    half8 z = {(_Float16)0,(_Float16)0,(_Float16)0,(_Float16)0,
               (_Float16)0,(_Float16)0,(_Float16)0,(_Float16)0};
    return z;
}

__device__ __forceinline__ half8 ld8(const _Float16* p) {
    return *reinterpret_cast<const half8*>(p);
}

__device__ __forceinline__ void lstm_cell(float ip, float fp, float gp, float op,
                                          float& c, float& h) {
    float ig = 1.0f / (1.0f + expf(-ip));
    float fg = 1.0f / (1.0f + expf(-fp));
    float og = 1.0f / (1.0f + expf(-op));
    float gv = tanhf(gp);
    c = fg * c + ig * gv;
    h = og * tanhf(c);
}

// One-shot census barrier: r5/r6-PROVEN full-threadfence barrier, own counters.
__device__ __forceinline__ void gsync_census(unsigned* bar) {
    __syncthreads();
    if (threadIdx.x == 0) {
        __threadfence();
        unsigned a = __hip_atomic_fetch_add(&bar[256 + (blockIdx.x & 15) * 16], 1u,
                                            __ATOMIC_RELAXED, __HIP_MEMORY_SCOPE_AGENT);
        if (a == 15u) {
            unsigned m = __hip_atomic_fetch_add(&bar[512], 1u,
                                                __ATOMIC_RELAXED, __HIP_MEMORY_SCOPE_AGENT);
            if (m == 15u)
                __hip_atomic_store(&bar[520], 1u,
                                   __ATOMIC_RELAXED, __HIP_MEMORY_SCOPE_AGENT);
        }
        while (__hip_atomic_load(&bar[520], __ATOMIC_RELAXED,
                                 __HIP_MEMORY_SCOPE_AGENT) < 1u)
            __builtin_amdgcn_s_sleep(2);
        __threadfence();
    }
    __syncthreads();
}

// Per-step barrier v5 — parallel slot arrival + WAVE-PARALLEL polls.
// r8 proved slot-arrival semantics correct but scanned serially (31 scalar L3
// RTs); here the leader's wave reads all local slots in ONE vector load per
// poll iteration, and the master/gen chain is replaced by 8 per-XCD done-flags
// (gslots) polled by lanes 0..15. Ordering chain (all primitives r5-r8-proven):
//   entry __syncthreads => every wave's plain h-stores retired in local L2;
//   non-leader sc1 slot store issued after that => leader observing slot=tgt
//   implies that block's h is in the shared L2; leader __threadfence() (wbl2+
//   inv, completion-waited) => whole XCD's h at L3; gslot store issued after
//   the fence => any block observing all gslots knows all h is at L3 and its
//   own L2 was invalidated by its own leader's fence; buffer_inv sc0 freshens
//   the CU L1. Slots/gslots are monotone (round+1), no resets.
__device__ __forceinline__ void gsync5(unsigned* bar, int round, unsigned g,
                                       unsigned rank, unsigned cnt,
                                       bool leader, bool gAct) {
    const unsigned tgt = (unsigned)(round + 1);
    __syncthreads();
    if (threadIdx.x < 64) {
        const int lane = threadIdx.x;
        if (leader) {
            // wave-parallel local poll: lane i watches rank i (1..cnt-1)
            for (;;) {
                bool ok = (lane == 0) || (lane >= (int)cnt);
                if (!ok) {
                    unsigned v = __hip_atomic_load(&bar[1024 + g * 64 + lane],
                                                   __ATOMIC_RELAXED,
                                                   __HIP_MEMORY_SCOPE_AGENT);
                    ok = (v >= tgt);
                }
                if (__all(ok)) break;
                __builtin_amdgcn_s_sleep(1);
            }
            __threadfence();               // wbl2+inv: whole XCD's h -> L3, completed
            if (lane == 0)
                __hip_atomic_store(&bar[3072 + g * 16], tgt,
                                   __ATOMIC_RELAXED, __HIP_MEMORY_SCOPE_AGENT);
        } else {
            if (lane == 0)
                __hip_atomic_store(&bar[1024 + g * 64 + rank], tgt,
                                   __ATOMIC_RELAXED, __HIP_MEMORY_SCOPE_AGENT);
        }
        // all blocks: wave-parallel poll of active XCDs' done-flags (lanes 0..15)
        for (;;) {
            bool ok = true;
            if (gAct) {
                unsigned v = __hip_atomic_load(&bar[3072 + lane * 16],
                                               __ATOMIC_RELAXED,
                                               __HIP_MEMORY_SCOPE_AGENT);
                ok = (v >= tgt);
            }
            if (__all(ok)) break;
            __builtin_amdgcn_s_sleep(2);
        }
        // per-CU L1 invalidate so post-barrier plain loads refetch via (fresh) L2
        asm volatile("buffer_inv sc0\n\ts_waitcnt vmcnt(0)" ::: "memory");
    }
    __syncthreads();
}

// ---------------- prep kernels ----------------
__global__ void k_cvt(const float* __restrict__ s, _Float16* __restrict__ d, int n) {
    for (int i = blockIdx.x * blockDim.x + threadIdx.x; i < n; i += gridDim.x * blockDim.x)
        d[i] = (_Float16)s[i];
}

__global__ void k_bias(const float* a1, const float* a2, const float* b1, const float* b2,
                       const float* c1, const float* c2,
                       float* sb, float* pb, float* bb) {
    int i = blockIdx.x * blockDim.x + threadIdx.x;
    if (i < 4096) {
        sb[i] = a1[i] + a2[i];
        pb[i] = b1[i] + b2[i];
        bb[i] = c1[i] + c2[i];
    }
}

// X16[t][row][d]; row 0 = headline, rows 1..128 = body sentences, 129..143 zero pad
__global__ void k_gather(const int* __restrict__ head, const int* __restrict__ body,
                         const float* __restrict__ emb, _Float16* __restrict__ X16) {
    const int total = 64 * MPAD * VD;
    for (int idx = blockIdx.x * blockDim.x + threadIdx.x; idx < total;
         idx += gridDim.x * blockDim.x) {
        int d   = idx & (VD - 1);
        int rt  = idx >> 9;
        int row = rt % MPAD;
        int t   = rt / MPAD;
        float v = 0.0f;
        if (row == 0)         v = emb[(size_t)head[t] * VD + d];
        else if (row < BSENT) v = emb[(size_t)body[(row - 1) * 64 + t] * VD + d];
        X16[idx] = (_Float16)v;
    }
}

// ---------------- main persistent kernel ----------------
// 256 blocks x 512 thr (8 waves). Block owns 4 hidden units (16 gate cols).
// Weights live in LDS (64 KB wfrag) — immune to the per-step L2 invalidate.
// Sentence: 9 row-tiles of 16; waves g=wv&3 own tiles {g, g+4, (g==0: 8)};
// K(1536) split 2-way across kh=wv>>2; epilogue reduces the two K-half partials.
extern "C" __global__ void __launch_bounds__(NTHR, 2)
k_main(const _Float16* __restrict__ sWih, const _Float16* __restrict__ sWhh,
       const _Float16* __restrict__ pWih, const _Float16* __restrict__ pWhh,
       const _Float16* __restrict__ bWih, const _Float16* __restrict__ bWhh,
       const float* __restrict__ sb, const float* __restrict__ pb, const float* __restrict__ bb,
       const _Float16* __restrict__ X16,
       _Float16* H, _Float16* HP, _Float16* HB,
       float* out, unsigned* bar)
{
    __shared__ float lds[8][3][16][17];
    __shared__ half8 wfrag[4096];     // 64 KB: B-fragments for the current stage
    __shared__ unsigned sMeta[4];     // g, rank, cnt, leader

    const int tid  = threadIdx.x;
    const int lane = tid & 63;
    const int wv   = tid >> 6;        // 0..7
    const int g    = wv & 3;
    const int kh   = wv >> 2;         // K-half
    const int l15  = lane & 15;
    const int krow = lane >> 4;       // 0..3
    const int rr   = lane >> 2;       // epilogue row 0..15
    const int mm   = lane & 3;        // epilogue col 0..3
    const int ubase = blockIdx.x * 4;
    const int uo    = ubase + mm;
    const int grow  = (l15 >> 2) * HM + ubase + (l15 & 3);  // weight row for B col l15

    const float sbi = sb[uo], sbf = sb[1024 + uo], sbg = sb[2048 + uo], sbo = sb[3072 + uo];
    const float pbi = pb[uo], pbf = pb[1024 + uo], pbg = pb[2048 + uo], pbo = pb[3072 + uo];
    const float bbi = bb[uo], bbf = bb[1024 + uo], bbg = bb[2048 + uo], bbo = bb[3072 + uo];

    const int rA0 = g * 16 + l15;     // tile g
    const int rA1 = rA0 + 64;         // tile g+4
    const int rA2 = 128 + l15;        // tile 8 (g==0 waves)

    float c_main = 0.f, c_t8 = 0.f, c_para = 0.f, c_body = 0.f, rhid_reg = 0.f;
    int round = 0;

    // ---- census: learn XCD, rank, blocks-per-XCD; broadcast via LDS ----
    {
        unsigned xcc = __builtin_amdgcn_s_getreg(XCC_ID_IMM) & 15u;
        unsigned rk = 0;
        if (tid == 0) {
            rk = __hip_atomic_fetch_add(&bar[xcc * 16], 1u,
                                        __ATOMIC_RELAXED, __HIP_MEMORY_SCOPE_AGENT);
        }
        // ---- stage sentence-stage weight fragments into LDS while census settles ----
#pragma unroll
        for (int q = 0; q < 2; ++q) {
            int kt = wv + q * 8;
            wfrag[kt * 64 + lane] = ld8(sWih + (size_t)grow * VD + kt * 32 + krow * 8);
        }
#pragma unroll
        for (int q = 0; q < 4; ++q) {
            int kt = wv + q * 8;
            wfrag[(16 + kt) * 64 + lane] = ld8(sWhh + (size_t)grow * HM + kt * 32 + krow * 8);
        }
        gsync_census(bar);
        if (tid == 0) {
            sMeta[0] = xcc;
            sMeta[1] = rk;
            sMeta[2] = __hip_atomic_load(&bar[xcc * 16], __ATOMIC_RELAXED,
                                         __HIP_MEMORY_SCOPE_AGENT);
            sMeta[3] = (rk == 0u) ? 1u : 0u;
        }
        __syncthreads();
    }
    const unsigned myG   = sMeta[0];
    const unsigned myRank = sMeta[1];
    const unsigned myCnt = sMeta[2];
    const bool     leader = (sMeta[3] != 0u);
    bool gAct = false;
    if (tid < 16) {
        gAct = (__hip_atomic_load(&bar[tid * 16], __ATOMIC_RELAXED,
                                  __HIP_MEMORY_SCOPE_AGENT) != 0u);
    }

    // ================= sentence LSTM: 64 steps, batch 129 (pad 144) =================
#pragma unroll 1
    for (int t = 0; t < 64; ++t) {
        const _Float16* Xt = X16 + (size_t)t * MPAD * VD;
        const _Float16* Hr = H + (size_t)(t & 1) * MPAD * HM;
        _Float16*       Hw = H + (size_t)((t + 1) & 1) * MPAD * HM;

        f32x4 a0 = {0.f,0.f,0.f,0.f}, a1 = {0.f,0.f,0.f,0.f}, a2 = {0.f,0.f,0.f,0.f};
        if (kh == 0) {
            // x part: K 0..511 (slots 0..15)
#pragma unroll
            for (int kt = 0; kt < 16; ++kt) {
                const int kk = kt * 32 + krow * 8;
                half8 b  = wfrag[kt * 64 + lane];
                half8 x0 = ld8(Xt + (size_t)rA0 * VD + kk);
                half8 x1 = ld8(Xt + (size_t)rA1 * VD + kk);
                a0 = __builtin_amdgcn_mfma_f32_16x16x32_f16(x0, b, a0, 0, 0, 0);
                a1 = __builtin_amdgcn_mfma_f32_16x16x32_f16(x1, b, a1, 0, 0, 0);
                if (g == 0) {
                    half8 x2 = ld8(Xt + (size_t)rA2 * VD + kk);
                    a2 = __builtin_amdgcn_mfma_f32_16x16x32_f16(x2, b, a2, 0, 0, 0);
                }
            }
            // h part: K-tiles 0..7 (slots 16..23)
#pragma unroll
            for (int kt = 0; kt < 8; ++kt) {
                const int kk = kt * 32 + krow * 8;
                half8 b  = wfrag[(16 + kt) * 64 + lane];
                half8 h0 = ld8(Hr + (size_t)rA0 * HM + kk);
                half8 h1 = ld8(Hr + (size_t)rA1 * HM + kk);
                a0 = __builtin_amdgcn_mfma_f32_16x16x32_f16(h0, b, a0, 0, 0, 0);
                a1 = __builtin_amdgcn_mfma_f32_16x16x32_f16(h1, b, a1, 0, 0, 0);
                if (g == 0) {
                    half8 h2 = ld8(Hr + (size_t)rA2 * HM + kk);
                    a2 = __builtin_amdgcn_mfma_f32_16x16x32_f16(h2, b, a2, 0, 0, 0);
                }
            }
        } else {
            // h part: K-tiles 8..31 (slots 24..47)
#pragma unroll
            for (int kt = 0; kt < 24; ++kt) {
                const int kk = (8 + kt) * 32 + krow * 8;
                half8 b  = wfrag[(24 + kt) * 64 + lane];
                half8 h0 = ld8(Hr + (size_t)rA0 * HM + kk);
                half8 h1 = ld8(Hr + (size_t)rA1 * HM + kk);
                a0 = __builtin_amdgcn_mfma_f32_16x16x32_f16(h0, b, a0, 0, 0, 0);
                a1 = __builtin_amdgcn_mfma_f32_16x16x32_f16(h1, b, a1, 0, 0, 0);
                if (g == 0) {
                    half8 h2 = ld8(Hr + (size_t)rA2 * HM + kk);
                    a2 = __builtin_amdgcn_mfma_f32_16x16x32_f16(h2, b, a2, 0, 0, 0);
                }
            }
        }
        // stash K-half partials
#pragma unroll
        for (int q = 0; q < 4; ++q) {
            lds[wv][0][krow * 4 + q][l15] = a0[q];
            lds[wv][1][krow * 4 + q][l15] = a1[q];
        }
        if (g == 0) {
#pragma unroll
            for (int q = 0; q < 4; ++q) lds[wv][2][krow * 4 + q][l15] = a2[q];
        }
        __syncthreads();
        // epilogue: wave T reduces the two K-half partials of tile T
        {
            const int T  = wv;
            const int wA = (T < 4) ? T     : T - 4;
            const int wB = (T < 4) ? T + 4 : T;
            const int jj = (T < 4) ? 0 : 1;
            const int rowg = T * 16 + rr;
            if (rowg < BSENT) {
                float ip = lds[wA][jj][rr][ 0 + mm] + lds[wB][jj][rr][ 0 + mm] + sbi;
                float fp = lds[wA][jj][rr][ 4 + mm] + lds[wB][jj][rr][ 4 + mm] + sbf;
                float gp = lds[wA][jj][rr][ 8 + mm] + lds[wB][jj][rr][ 8 + mm] + sbg;
                float op = lds[wA][jj][rr][12 + mm] + lds[wB][jj][rr][12 + mm] + sbo;
                float h;
                lstm_cell(ip, fp, gp, op, c_main, h);
                if (t == 63 && wv == 0 && rr == 0) rhid_reg = h;
                Hw[(size_t)rowg * HM + uo] = (_Float16)h;
            }
        }
        if (wv == 0) {   // tile 8: only row 128 valid
            const int rowg = 128 + rr;
            if (rowg < BSENT) {
                float ip = lds[0][2][rr][ 0 + mm] + lds[4][2][rr][ 0 + mm] + sbi;
                float fp = lds[0][2][rr][ 4 + mm] + lds[4][2][rr][ 4 + mm] + sbf;
                float gp = lds[0][2][rr][ 8 + mm] + lds[4][2][rr][ 8 + mm] + sbg;
                float op = lds[0][2][rr][12 + mm] + lds[4][2][rr][12 + mm] + sbo;
                float h;
                lstm_cell(ip, fp, gp, op, c_t8, h);
                Hw[(size_t)rowg * HM + uo] = (_Float16)h;
            }
        }
        gsync5(bar, round, myG, myRank, myCnt, leader, gAct); ++round;
    }

    // ---- stage paragraph-stage weights: ih kt0..31 -> slot kt, hh -> slot 32+kt ----
#pragma unroll
    for (int q = 0; q < 4; ++q) {
        int kt = wv + q * 8;
        wfrag[kt * 64 + lane]        = ld8(pWih + (size_t)grow * HM + kt * 32 + krow * 8);
        wfrag[(32 + kt) * 64 + lane] = ld8(pWhh + (size_t)grow * HM + kt * 32 + krow * 8);
    }
    __syncthreads();

    // ================= paragraph LSTM: 16 steps, batch 8 (pad 16) =================
    const _Float16* Hs = H;   // sentence-final h landed in buffer 0
#pragma unroll 1
    for (int s = 0; s < 16; ++s) {
        const _Float16* HPr = HP + (size_t)s * 8 * HM;
        _Float16*       HPw = HP + (size_t)(s + 1) * 8 * HM;
        f32x4 acc = {0.f,0.f,0.f,0.f};
        if (wv < 4) {
            const int rs = 1 + l15 * 16 + s;                  // sent_h[p=l15][s]
#pragma unroll
            for (int k = 0; k < 8; ++k) {
                const int kt = wv * 8 + k;
                const int kk = kt * 32 + krow * 8;
                half8 b = wfrag[kt * 64 + lane];
                half8 a = h8z();
                if (l15 < 8) a = ld8(Hs + (size_t)rs * HM + kk);
                acc = __builtin_amdgcn_mfma_f32_16x16x32_f16(a, b, acc, 0, 0, 0);
            }
        } else {
#pragma unroll
            for (int k = 0; k < 8; ++k) {
                const int kt = (wv - 4) * 8 + k;
                const int kk = kt * 32 + krow * 8;
                half8 b = wfrag[(32 + kt) * 64 + lane];
                half8 a = h8z();
                if (l15 < 8) a = ld8(HPr + (size_t)l15 * HM + kk);
                acc = __builtin_amdgcn_mfma_f32_16x16x32_f16(a, b, acc, 0, 0, 0);
            }
        }
#pragma unroll
        for (int q = 0; q < 4; ++q) lds[wv][0][krow * 4 + q][l15] = acc[q];
        __syncthreads();
        if (wv == 0 && rr < 8) {
            float ip = pbi, fp = pbf, gp = pbg, op = pbo;
#pragma unroll
            for (int w = 0; w < 8; ++w) {
                ip += lds[w][0][rr][ 0 + mm];
                fp += lds[w][0][rr][ 4 + mm];
                gp += lds[w][0][rr][ 8 + mm];
                op += lds[w][0][rr][12 + mm];
            }
            float h;
            lstm_cell(ip, fp, gp, op, c_para, h);
            HPw[(size_t)rr * HM + uo] = (_Float16)h;
        }
        gsync5(bar, round, myG, myRank, myCnt, leader, gAct); ++round;
    }

    // ---- stage body-stage weights (same slot scheme) ----
#pragma unroll
    for (int q = 0; q < 4; ++q) {
        int kt = wv + q * 8;
        wfrag[kt * 64 + lane]        = ld8(bWih + (size_t)grow * HM + kt * 32 + krow * 8);
        wfrag[(32 + kt) * 64 + lane] = ld8(bWhh + (size_t)grow * HM + kt * 32 + krow * 8);
    }
    __syncthreads();

    // ================= body LSTM: 8 steps, batch 1 =================
    const _Float16* HPf = HP + (size_t)16 * 8 * HM;   // para-final h
#pragma unroll 1
    for (int t = 0; t < 8; ++t) {
        const _Float16* HBr = HB + (size_t)t * HM;
        _Float16*       HBw = HB + (size_t)(t + 1) * HM;
        f32x4 acc = {0.f,0.f,0.f,0.f};
        if (wv < 4) {
#pragma unroll
            for (int k = 0; k < 8; ++k) {
                const int kt = wv * 8 + k;
                const int kk = kt * 32 + krow * 8;
                half8 b = wfrag[kt * 64 + lane];
                half8 a = h8z();
                if (l15 == 0) a = ld8(HPf + (size_t)t * HM + kk);
                acc = __builtin_amdgcn_mfma_f32_16x16x32_f16(a, b, acc, 0, 0, 0);
            }
        } else {
#pragma unroll
            for (int k = 0; k < 8; ++k) {
                const int kt = (wv - 4) * 8 + k;
                const int kk = kt * 32 + krow * 8;
                half8 b = wfrag[(32 + kt) * 64 + lane];
                half8 a = h8z();
                if (l15 == 0) a = ld8(HBr + kk);
                acc = __builtin_amdgcn_mfma_f32_16x16x32_f16(a, b, acc, 0, 0, 0);
            }
        }
#pragma unroll
        for (int q = 0; q < 4; ++q) lds[wv][0][krow * 4 + q][l15] = acc[q];
        __syncthreads();
        if (wv == 0 && rr == 0) {   // lanes 0..3
            float ip = bbi, fp = bbf, gp = bbg, op = bbo;
#pragma unroll
            for (int w = 0; w < 8; ++w) {
                ip += lds[w][0][0][ 0 + mm];
                fp += lds[w][0][0][ 4 + mm];
                gp += lds[w][0][0][ 8 + mm];
                op += lds[w][0][0][12 + mm];
            }
            float h;
            lstm_cell(ip, fp, gp, op, c_body, h);
            HBw[uo] = (_Float16)h;
            if (t == 7) {
                out[uo]        = h;          // h_body
                out[1024 + uo] = rhid_reg;   // r_hidden
            }
        }
        gsync5(bar, round, myG, myRank, myCnt, leader, gAct); ++round;
    }
}

// ---------------- host ----------------
extern "C" void kernel_launch(void* const* d_in, const int* in_sizes, int n_in,
                              void* d_out, int out_size, void* d_ws, size_t ws_size,
                              hipStream_t stream) {
    const int*   head  = (const int*)d_in[0];
    const int*   body  = (const int*)d_in[1];
    const float* emb   = (const float*)d_in[2];
    const float* sWihF = (const float*)d_in[3];
    const float* sWhhF = (const float*)d_in[4];
    const float* sbih  = (const float*)d_in[5];
    const float* sbhh  = (const float*)d_in[6];
    const float* pWihF = (const float*)d_in[7];
    const float* pWhhF = (const float*)d_in[8];
    const float* pbih  = (const float*)d_in[9];
    const float* pbhh  = (const float*)d_in[10];
    const float* bWihF = (const float*)d_in[11];
    const float* bWhhF = (const float*)d_in[12];
    const float* bbih  = (const float*)d_in[13];
    const float* bbhh  = (const float*)d_in[14];

    char* ws = (char*)d_ws;
    _Float16* sWih16 = (_Float16*)(ws + OFF_SWIH);
    _Float16* sWhh16 = (_Float16*)(ws + OFF_SWHH);
    _Float16* pWih16 = (_Float16*)(ws + OFF_PWIH);
    _Float16* pWhh16 = (_Float16*)(ws + OFF_PWHH);
    _Float16* bWih16 = (_Float16*)(ws + OFF_BWIH);
    _Float16* bWhh16 = (_Float16*)(ws + OFF_BWHH);
    float*    sbp    = (float*)(ws + OFF_SB);
    float*    pbp    = (float*)(ws + OFF_PB);
    float*    bbp    = (float*)(ws + OFF_BB);
    _Float16* X16    = (_Float16*)(ws + OFF_X16);
    _Float16* Hp     = (_Float16*)(ws + OFF_H);
    _Float16* HPp    = (_Float16*)(ws + OFF_HP);
    _Float16* HBp    = (_Float16*)(ws + OFF_HB);
    unsigned* barp   = (unsigned*)(ws + OFF_BAR);
    float*    outp   = (float*)d_out;

    hipMemsetAsync(ws + OFF_STATE, 0, STATE_BYTES, stream);
    k_cvt<<<512, 256, 0, stream>>>(sWihF, sWih16, 4096 * 512);
    k_cvt<<<1024, 256, 0, stream>>>(sWhhF, sWhh16, 4096 * 1024);
    k_cvt<<<1024, 256, 0, stream>>>(pWihF, pWih16, 4096 * 1024);
    k_cvt<<<1024, 256, 0, stream>>>(pWhhF, pWhh16, 4096 * 1024);
    k_cvt<<<1024, 256, 0, stream>>>(bWihF, bWih16, 4096 * 1024);
    k_cvt<<<1024, 256, 0, stream>>>(bWhhF, bWhh16, 4096 * 1024);
    k_bias<<<16, 256, 0, stream>>>(sbih, sbhh, pbih, pbhh, bbih, bbhh, sbp, pbp, bbp);
    k_gather<<<2048, 256, 0, stream>>>(head, body, emb, X16);

    void* args[] = { &sWih16, &sWhh16, &pWih16, &pWhh16, &bWih16, &bWhh16,
                     &sbp, &pbp, &bbp, &X16,
                     &Hp, &HPp, &HBp, &outp, &barp };
    hipError_t err = hipLaunchCooperativeKernel(reinterpret_cast<void*>(k_main),
                                                dim3(NBLK), dim3(NTHR), args, 0, stream);
    if (err != hipSuccess) {
        // 256 blocks x 512 thr = 8 waves/CU on 256 CUs are co-resident; best-effort fallback.
        k_main<<<NBLK, NTHR, 0, stream>>>(sWih16, sWhh16, pWih16, pWhh16, bWih16, bWhh16,
                                          sbp, pbp, bbp, X16,
                                          Hp, HPp, HBp, outp, barp);
    }
}